// Round 6
// baseline (28.389 us; speedup 1.0000x reference)
//
#include <hip/hip_runtime.h>
#include <math.h>

// DETR HungarianMatcher cost matrix on MI355X — round 6 (R5 + compile fix).
// A: p2[n][c] = 2 - softmax(logits[n])[c]  -> d_ws   (one wave per row)
// B: C[n,m] = 5*L1 + p2[n,lbl[m]] - 2*iou - 2*uni/ae (grid-stride streaming,
//    targets in registers, uniform pred-box loads, nontemporal float4 stores)
// Fix: __builtin_nontemporal_store needs a NATIVE vector type, not HIP's
// float4 class -> use ext_vector_type(4) alias.

#define NROWS 16000
#define NC 92
#define M_TGT 1024
#define TPB 256
#define KPT 4        // consecutive targets per thread (KPT*TPB == M_TGT)
#define GRID_B 2000  // kernel B blocks; 16000/2000 = 8 rows per block

typedef float f32x4 __attribute__((ext_vector_type(4)));

// ---------------- Kernel A: softmax -> p2 ----------------
__global__ __launch_bounds__(TPB) void softmax_p2_kernel(
    const float* __restrict__ logits,   // [NROWS, NC]
    float* __restrict__ p2)             // [NROWS, NC] = 2 - prob
{
    const int lane = threadIdx.x & 63;
    const int row  = blockIdx.x * 4 + (threadIdx.x >> 6);
    const float* lg = logits + (size_t)row * NC;
    const float x0 = lg[lane];                 // lanes 0..63
    const bool  hi = (lane < NC - 64);         // lanes 0..27 cover 64..91
    const float x1 = hi ? lg[64 + lane] : -INFINITY;
    float mx = fmaxf(x0, x1);
    #pragma unroll
    for (int off = 32; off >= 1; off >>= 1)
        mx = fmaxf(mx, __shfl_xor(mx, off));
    const float e0 = __expf(x0 - mx);
    const float e1 = hi ? __expf(x1 - mx) : 0.0f;
    float s = e0 + e1;
    #pragma unroll
    for (int off = 32; off >= 1; off >>= 1)
        s += __shfl_xor(s, off);
    const float rs = __builtin_amdgcn_rcpf(s);
    float* pr = p2 + (size_t)row * NC;
    pr[lane] = fmaf(-e0, rs, 2.0f);
    if (hi) pr[64 + lane] = fmaf(-e1, rs, 2.0f);
}

// ---------------- Kernel B: streaming cost ----------------
__global__ __launch_bounds__(TPB) void cost_kernel(
    const float* __restrict__ p2,       // [NROWS, NC]
    const float* __restrict__ pboxes,   // [NROWS, 4] cxcywh
    const float* __restrict__ tboxes,   // [M_TGT, 4] cxcywh
    const int*   __restrict__ tlabels,  // [M_TGT]
    float* __restrict__ out)            // [NROWS, M_TGT]
{
    const int t = threadIdx.x;

    // per-thread target context (registers), m = 4t + k
    float tcx[KPT], tcy[KPT], twd[KPT], tht[KPT];
    float bx0[KPT], by0[KPT], bx1[KPT], by1[KPT], areab[KPT];
    const int4 lb4 = reinterpret_cast<const int4*>(tlabels)[t];
    int lbl[KPT] = {lb4.x, lb4.y, lb4.z, lb4.w};
    #pragma unroll
    for (int k = 0; k < KPT; ++k) {
        const float4 tb = reinterpret_cast<const float4*>(tboxes)[4 * t + k];
        tcx[k] = tb.x; tcy[k] = tb.y; twd[k] = tb.z; tht[k] = tb.w;
        bx0[k] = fmaf(-0.5f, tb.z, tb.x);  by0[k] = fmaf(-0.5f, tb.w, tb.y);
        bx1[k] = fmaf( 0.5f, tb.z, tb.x);  by1[k] = fmaf( 0.5f, tb.w, tb.y);
        areab[k] = tb.z * tb.w;
        lbl[k] = (lbl[k] < 0) ? 0 : (lbl[k] > NC - 1 ? NC - 1 : lbl[k]);
    }

    #pragma unroll 2
    for (int n = blockIdx.x; n < NROWS; n += GRID_B) {
        // uniform pred box -> scalar load + broadcast
        const float4 pb = reinterpret_cast<const float4*>(pboxes)[n];
        const float ax0 = fmaf(-0.5f, pb.z, pb.x);
        const float ay0 = fmaf(-0.5f, pb.w, pb.y);
        const float ax1 = fmaf( 0.5f, pb.z, pb.x);
        const float ay1 = fmaf( 0.5f, pb.w, pb.y);
        const float area_a = pb.z * pb.w;
        const float* __restrict__ pr = p2 + (size_t)n * NC;

        float tmp[KPT];
        #pragma unroll
        for (int k = 0; k < KPT; ++k) {
            const float cls2 = pr[lbl[k]];   // 2 - prob[target class], L1/L2 hit
            const float cb = fabsf(pb.x - tcx[k]) + fabsf(pb.y - tcy[k])
                           + fabsf(pb.z - twd[k]) + fabsf(pb.w - tht[k]);
            const float iwu = fminf(ax1, bx1[k]) - fmaxf(ax0, bx0[k]);
            const float ihu = fminf(ay1, by1[k]) - fmaxf(ay0, by0[k]);
            const float inter = fmaxf(iwu, 0.0f) * fmaxf(ihu, 0.0f);
            const float uni = area_a + areab[k] - inter;
            const float ew = pb.z + twd[k] - iwu;   // max(a1,b1)-min(a0,b0)
            const float eh = pb.w + tht[k] - ihu;
            const float ae = ew * eh;
            const float h = fmaf(inter, __builtin_amdgcn_rcpf(uni),
                                 uni * __builtin_amdgcn_rcpf(ae));
            tmp[k] = fmaf(5.0f, cb, cls2) - 2.0f * h;
        }
        f32x4 res = {tmp[0], tmp[1], tmp[2], tmp[3]};
        __builtin_nontemporal_store(res,
            reinterpret_cast<f32x4*>(out + ((size_t)n << 10)) + t);
    }
}

// ---------------- Fallback mono-kernel (R4) if ws too small ----------------
#define ROWS 16
__global__ __launch_bounds__(TPB) void hungarian_mono_kernel(
    const float* __restrict__ logits, const float* __restrict__ pboxes,
    const float* __restrict__ tboxes, const int* __restrict__ tlabels,
    float* __restrict__ out)
{
    const int n0 = blockIdx.x * ROWS;
    const int t = threadIdx.x;
    const int lane = t & 63;
    const int wid  = t >> 6;
    __shared__ float negp[ROWS][NC];
    #pragma unroll
    for (int j = 0; j < 4; ++j) {
        const int r = wid * 4 + j;
        const float* lg = logits + (size_t)(n0 + r) * NC;
        const float x0 = lg[lane];
        const bool  hi = (lane < NC - 64);
        const float x1 = hi ? lg[64 + lane] : -INFINITY;
        float mx = fmaxf(x0, x1);
        #pragma unroll
        for (int off = 32; off >= 1; off >>= 1)
            mx = fmaxf(mx, __shfl_xor(mx, off));
        const float e0 = __expf(x0 - mx);
        const float e1 = hi ? __expf(x1 - mx) : 0.0f;
        float s = e0 + e1;
        #pragma unroll
        for (int off = 32; off >= 1; off >>= 1)
            s += __shfl_xor(s, off);
        const float rs = __builtin_amdgcn_rcpf(s);
        negp[r][lane] = fmaf(-e0, rs, 2.0f);
        if (hi) negp[r][64 + lane] = fmaf(-e1, rs, 2.0f);
    }
    float tcx[KPT], tcy[KPT], twd[KPT], tht[KPT];
    float bx0[KPT], by0[KPT], bx1[KPT], by1[KPT], areab[KPT];
    const int4 lb4 = reinterpret_cast<const int4*>(tlabels)[t];
    int lbl[KPT] = {lb4.x, lb4.y, lb4.z, lb4.w};
    #pragma unroll
    for (int k = 0; k < KPT; ++k) {
        const float4 tb = reinterpret_cast<const float4*>(tboxes)[4 * t + k];
        tcx[k] = tb.x; tcy[k] = tb.y; twd[k] = tb.z; tht[k] = tb.w;
        bx0[k] = fmaf(-0.5f, tb.z, tb.x);  by0[k] = fmaf(-0.5f, tb.w, tb.y);
        bx1[k] = fmaf( 0.5f, tb.z, tb.x);  by1[k] = fmaf( 0.5f, tb.w, tb.y);
        areab[k] = tb.z * tb.w;
        lbl[k] = (lbl[k] < 0) ? 0 : (lbl[k] > NC - 1 ? NC - 1 : lbl[k]);
    }
    __syncthreads();
    #pragma unroll 4
    for (int r = 0; r < ROWS; ++r) {
        const float4 pb = reinterpret_cast<const float4*>(pboxes)[n0 + r];
        const float ax0 = fmaf(-0.5f, pb.z, pb.x);
        const float ay0 = fmaf(-0.5f, pb.w, pb.y);
        const float ax1 = fmaf( 0.5f, pb.z, pb.x);
        const float ay1 = fmaf( 0.5f, pb.w, pb.y);
        const float area_a = pb.z * pb.w;
        const float* __restrict__ np = negp[r];
        float tmp[KPT];
        #pragma unroll
        for (int k = 0; k < KPT; ++k) {
            const float cls2 = np[lbl[k]];
            const float cb = fabsf(pb.x - tcx[k]) + fabsf(pb.y - tcy[k])
                           + fabsf(pb.z - twd[k]) + fabsf(pb.w - tht[k]);
            const float iwu = fminf(ax1, bx1[k]) - fmaxf(ax0, bx0[k]);
            const float ihu = fminf(ay1, by1[k]) - fmaxf(ay0, by0[k]);
            const float inter = fmaxf(iwu, 0.0f) * fmaxf(ihu, 0.0f);
            const float uni = area_a + areab[k] - inter;
            const float ew = pb.z + twd[k] - iwu;
            const float eh = pb.w + tht[k] - ihu;
            const float ae = ew * eh;
            const float h = fmaf(inter, __builtin_amdgcn_rcpf(uni),
                                 uni * __builtin_amdgcn_rcpf(ae));
            tmp[k] = fmaf(5.0f, cb, cls2) - 2.0f * h;
        }
        float4 res = {tmp[0], tmp[1], tmp[2], tmp[3]};
        reinterpret_cast<float4*>(out + ((size_t)(n0 + r) << 10))[t] = res;
    }
}

extern "C" void kernel_launch(void* const* d_in, const int* in_sizes, int n_in,
                              void* d_out, int out_size, void* d_ws, size_t ws_size,
                              hipStream_t stream) {
    const float* logits  = (const float*)d_in[0];  // [16,1000,92]
    const float* pboxes  = (const float*)d_in[1];  // [16,1000,4]
    const float* tboxes  = (const float*)d_in[2];  // [1024,4]
    const int*   tlabels = (const int*)d_in[3];    // [1024]
    float* out = (float*)d_out;                    // [16,1000,1024]

    const size_t p2_bytes = (size_t)NROWS * NC * sizeof(float);
    if (ws_size >= p2_bytes) {
        float* p2 = (float*)d_ws;
        softmax_p2_kernel<<<NROWS / 4, TPB, 0, stream>>>(logits, p2);
        cost_kernel<<<GRID_B, TPB, 0, stream>>>(p2, pboxes, tboxes, tlabels, out);
    } else {
        hungarian_mono_kernel<<<NROWS / ROWS, TPB, 0, stream>>>(
            logits, pboxes, tboxes, tlabels, out);
    }
}

// Round 7
// 22.405 us; speedup vs baseline: 1.2671x; 1.2671x over previous
//
#include <hip/hip_runtime.h>
#include <math.h>

// DETR HungarianMatcher cost matrix on MI355X — round 7: latency attack.
// Mono-kernel, ROWS=8 rows/block, 2000 blocks (31 waves/CU), software-
// pipelined prefetch of next row's class-prob gathers + pred box, so the
// serial {s_load pb -> LDS gather -> math -> store} chain of each row
// overlaps the previous row's compute. Nontemporal float4 stores.

#define NROWS 16000
#define NC 92
#define M_TGT 1024
#define TPB 256
#define ROWS 8
#define KPT 4   // consecutive targets per thread (KPT*TPB == M_TGT)

typedef float f32x4 __attribute__((ext_vector_type(4)));

__global__ __launch_bounds__(TPB, 6) void hungarian_cost_kernel(
    const float* __restrict__ logits,   // [NROWS, NC]
    const float* __restrict__ pboxes,   // [NROWS, 4] cxcywh
    const float* __restrict__ tboxes,   // [M_TGT, 4] cxcywh
    const int*   __restrict__ tlabels,  // [M_TGT]
    float* __restrict__ out)            // [NROWS, M_TGT]
{
    const int n0 = blockIdx.x * ROWS;
    const int t = threadIdx.x;
    const int lane = t & 63;
    const int wid  = t >> 6;

    __shared__ float negp[ROWS][NC];   // 2 - softmax prob

    // ---- softmax: wave `wid` handles rows 2*wid, 2*wid+1 ----
    #pragma unroll
    for (int j = 0; j < 2; ++j) {
        const int r = wid * 2 + j;
        const float* lg = logits + (size_t)(n0 + r) * NC;
        const float x0 = lg[lane];                 // lanes 0..63
        const bool  hi = (lane < NC - 64);         // lanes 0..27 cover 64..91
        const float x1 = hi ? lg[64 + lane] : -INFINITY;
        float mx = fmaxf(x0, x1);
        #pragma unroll
        for (int off = 32; off >= 1; off >>= 1)
            mx = fmaxf(mx, __shfl_xor(mx, off));
        const float e0 = __expf(x0 - mx);
        const float e1 = hi ? __expf(x1 - mx) : 0.0f;
        float s = e0 + e1;
        #pragma unroll
        for (int off = 32; off >= 1; off >>= 1)
            s += __shfl_xor(s, off);
        const float rs = __builtin_amdgcn_rcpf(s);
        negp[r][lane] = fmaf(-e0, rs, 2.0f);
        if (hi) negp[r][64 + lane] = fmaf(-e1, rs, 2.0f);
    }

    // ---- per-thread target context (registers), m = 4t + k ----
    float tcx[KPT], tcy[KPT], twd[KPT], tht[KPT];
    float bx0[KPT], by0[KPT], bx1[KPT], by1[KPT], areab[KPT];
    const int4 lb4 = reinterpret_cast<const int4*>(tlabels)[t];
    int lbl[KPT] = {lb4.x, lb4.y, lb4.z, lb4.w};
    #pragma unroll
    for (int k = 0; k < KPT; ++k) {
        const float4 tb = reinterpret_cast<const float4*>(tboxes)[4 * t + k];
        tcx[k] = tb.x; tcy[k] = tb.y; twd[k] = tb.z; tht[k] = tb.w;
        bx0[k] = fmaf(-0.5f, tb.z, tb.x);  by0[k] = fmaf(-0.5f, tb.w, tb.y);
        bx1[k] = fmaf( 0.5f, tb.z, tb.x);  by1[k] = fmaf( 0.5f, tb.w, tb.y);
        areab[k] = tb.z * tb.w;
        lbl[k] = (lbl[k] < 0) ? 0 : (lbl[k] > NC - 1 ? NC - 1 : lbl[k]);
    }
    __syncthreads();

    // ---- software-pipelined main loop over 8 rows ----
    float cls[KPT];                      // current row's gathered class cost
    #pragma unroll
    for (int k = 0; k < KPT; ++k) cls[k] = negp[0][lbl[k]];
    float4 pb = reinterpret_cast<const float4*>(pboxes)[n0];   // uniform

    #pragma unroll
    for (int r = 0; r < ROWS; ++r) {
        // prefetch next row's gathers + pred box (independent of this row)
        float clsN[KPT];
        float4 pbN;
        if (r + 1 < ROWS) {
            #pragma unroll
            for (int k = 0; k < KPT; ++k) clsN[k] = negp[r + 1][lbl[k]];
            pbN = reinterpret_cast<const float4*>(pboxes)[n0 + r + 1];
        }

        const float ax0 = fmaf(-0.5f, pb.z, pb.x);
        const float ay0 = fmaf(-0.5f, pb.w, pb.y);
        const float ax1 = fmaf( 0.5f, pb.z, pb.x);
        const float ay1 = fmaf( 0.5f, pb.w, pb.y);
        const float area_a = pb.z * pb.w;

        float tmp[KPT];
        #pragma unroll
        for (int k = 0; k < KPT; ++k) {
            const float cb = fabsf(pb.x - tcx[k]) + fabsf(pb.y - tcy[k])
                           + fabsf(pb.z - twd[k]) + fabsf(pb.w - tht[k]);
            const float iwu = fminf(ax1, bx1[k]) - fmaxf(ax0, bx0[k]);
            const float ihu = fminf(ay1, by1[k]) - fmaxf(ay0, by0[k]);
            const float inter = fmaxf(iwu, 0.0f) * fmaxf(ihu, 0.0f);
            const float uni = area_a + areab[k] - inter;
            const float ew = pb.z + twd[k] - iwu;   // max(a1,b1)-min(a0,b0)
            const float eh = pb.w + tht[k] - ihu;
            const float ae = ew * eh;
            const float h = fmaf(inter, __builtin_amdgcn_rcpf(uni),
                                 uni * __builtin_amdgcn_rcpf(ae));
            tmp[k] = fmaf(5.0f, cb, cls[k]) - 2.0f * h;
        }
        f32x4 res = {tmp[0], tmp[1], tmp[2], tmp[3]};
        __builtin_nontemporal_store(res,
            reinterpret_cast<f32x4*>(out + ((size_t)(n0 + r) << 10)) + t);

        #pragma unroll
        for (int k = 0; k < KPT; ++k) cls[k] = clsN[k];
        pb = pbN;
    }
}

extern "C" void kernel_launch(void* const* d_in, const int* in_sizes, int n_in,
                              void* d_out, int out_size, void* d_ws, size_t ws_size,
                              hipStream_t stream) {
    const float* logits  = (const float*)d_in[0];  // [16,1000,92]
    const float* pboxes  = (const float*)d_in[1];  // [16,1000,4]
    const float* tboxes  = (const float*)d_in[2];  // [1024,4]
    const int*   tlabels = (const int*)d_in[3];    // [1024]
    float* out = (float*)d_out;                    // [16,1000,1024]

    hungarian_cost_kernel<<<NROWS / ROWS, TPB, 0, stream>>>(
        logits, pboxes, tboxes, tlabels, out);
}